// Round 2
// baseline (2528.252 us; speedup 1.0000x reference)
//
#include <hip/hip_runtime.h>
#include <hip/hip_fp16.h>
#include <math.h>

// B=65536 rows, DIM=256, OUT=10.
// z = x@w_in + b_in; 4x { z = (z + tanh(z) + b_i) @ inv(W_i) }; out = softmax(z@w_out + b_out).
// Newton on a linear system converges in one step => z = c @ W^{-1}.
// Round 16: slab-pipelined persistent fused kernel, SPILL-FIXED.
//   256 blocks x 1024 threads (16 waves, 1 block/CU), 256 rows/block = 4 slabs x 64.
//   Wave w owns cols [w*16, w*16+16): per-layer weight slice = 32 VGPRs, loaded ONCE
//   per layer per block and reused for 4 slabs.
//   R15 spilled (~43 dw/thread scratch: WRITE_SIZE 2.5->45.6 MB): double acc (32) +
//   wreg (32) + full-unroll zf hoist blew the 128-VGPR/wave cap (16 waves/block).
//   Fix: SINGLE acc[4] (EPI reads it, next MFMA rewrites it - true dep, still
//   pipelinable per-mt) + unroll 2 on kc (caps live zf), as in the round-10 winner.
//   z planes: 4 x 64x256 fp16, XOR swizzle idx16(r,k) = r*256 + ((k>>3)^(r&31))*8 + (k&7).

typedef __attribute__((ext_vector_type(8))) short short8;
typedef __attribute__((ext_vector_type(4))) float f32x4;

// ---- helpers ----
__device__ __forceinline__ float tanh_fast(float x) {
#if __has_builtin(__builtin_amdgcn_exp2f)
  float e = __builtin_amdgcn_exp2f(x * 2.8853900817779268f);
#else
  float e = __expf(2.0f * x);
#endif
  return 1.0f - 2.0f * __builtin_amdgcn_rcpf(e + 1.0f);
}
// RNE pair pack (cold path: weights)
__device__ __forceinline__ unsigned rn_pair16(float v0, float v1) {
  __half2 h = __floats2half2_rn(v0, v1);
  return *reinterpret_cast<unsigned*>(&h);
}
// RTZ pair pack, single v_cvt_pkrtz (hot path: z)
__device__ __forceinline__ unsigned rtz_pair16(float v0, float v1) {
#if __has_builtin(__builtin_amdgcn_cvt_pkrtz)
  typedef __fp16 h2v __attribute__((ext_vector_type(2)));
  h2v h = __builtin_amdgcn_cvt_pkrtz(v0, v1);
  return *reinterpret_cast<unsigned*>(&h);
#else
  return rn_pair16(v0, v1);
#endif
}

// ---------------- Phase 1: one kernel, 384 blocks (unchanged) ----------------
// Blocks 0..255: matrix m = bid>>6, 4-row slab r0 = (bid&63)*4:
//   P = 6I -15W +20W^2 -15W^3 +6W^4 -W^5 via 4 Horner steps (mult by original W);
//   pack fp16-RNE into pk layer m+1.
// Blocks 256..383: pack w_in + w_out (at 5*32768, cols>=10 zero).
// pk layout (dwords): layer*32768 + kc*4096 + cg*256 + lane*4 + d;
// word d of lane(quad,n16) = M[kb][n] lo16 | M[kb+1][n] hi16, kb=kc*32+quad*8+2d, n=cg*16+n16.
__global__ __launch_bounds__(256) void ns_poly_k(
    const float* __restrict__ w1, const float* __restrict__ w2,
    const float* __restrict__ w3, const float* __restrict__ w4,
    const float* __restrict__ w_in, const float* __restrict__ w_out,
    unsigned* __restrict__ pk) {
  const int bid = blockIdx.x;
  const int t = threadIdx.x;
  if (bid >= 256) {
    int idx = (bid - 256) * 256 + t;  // 0..32767
    {
      int kc = idx >> 12;
      int nt = (idx >> 8) & 15;
      int lane = (idx >> 2) & 63;
      int d = idx & 3;
      int n = nt * 16 + (lane & 15);
      int kb = kc * 32 + (lane >> 4) * 8 + d * 2;
      pk[idx] = rn_pair16(w_in[kb * 256 + n], w_in[(kb + 1) * 256 + n]);
    }
    int idx2 = idx + 32768;
    if (idx2 < 34816) {
      int r2 = idx2 - 32768;  // 0..2047
      int kc = r2 >> 8;
      int lane = (r2 >> 2) & 63;
      int d = r2 & 3;
      int n = lane & 15;
      int kb = kc * 32 + (lane >> 4) * 8 + d * 2;
      float v0 = (n < 10) ? w_out[kb * 10 + n] : 0.0f;
      float v1 = (n < 10) ? w_out[(kb + 1) * 10 + n] : 0.0f;
      pk[5 * 32768 + r2] = rn_pair16(v0, v1);
    }
    return;
  }
  const int m = bid >> 6;           // matrix 0..3
  const int r0 = (bid & 63) * 4;    // slab start row (4 rows)
  const float* __restrict__ W = (m == 0) ? w1 : (m == 1) ? w2 : (m == 2) ? w3 : w4;
  __shared__ float S[4][256];

  // init: P = 6I - W (slab rows r0..r0+3)
#pragma unroll
  for (int i = 0; i < 4; ++i) {
    int e = i * 256 + t;
    int r = e >> 8, c = e & 255;
    S[r][c] = (((r0 + r) == c) ? 6.0f : 0.0f) - W[(r0 + r) * 256 + c];
  }
  __syncthreads();

  const float coef[4] = {-15.0f, 20.0f, -15.0f, 6.0f};
#pragma unroll
  for (int step = 0; step < 4; ++step) {
    float acc[4];
#pragma unroll
    for (int r = 0; r < 4; ++r) acc[r] = 0.0f;
    for (int k = 0; k < 256; k += 4) {
      float4 sv[4];
#pragma unroll
      for (int r = 0; r < 4; ++r) sv[r] = *(const float4*)&S[r][k];
      float wv0 = W[(k + 0) * 256 + t];
      float wv1 = W[(k + 1) * 256 + t];
      float wv2 = W[(k + 2) * 256 + t];
      float wv3 = W[(k + 3) * 256 + t];
#pragma unroll
      for (int r = 0; r < 4; ++r) {
        acc[r] = fmaf(sv[r].x, wv0, acc[r]);
        acc[r] = fmaf(sv[r].y, wv1, acc[r]);
        acc[r] = fmaf(sv[r].z, wv2, acc[r]);
        acc[r] = fmaf(sv[r].w, wv3, acc[r]);
      }
    }
    __syncthreads();
    float cdiag = coef[step];
#pragma unroll
    for (int r = 0; r < 4; ++r)
      S[r][t] = acc[r] + (((r0 + r) == t) ? cdiag : 0.0f);
    __syncthreads();
  }

  // ---- pack slab: kc = r0>>5, quad = (r0>>3)&3, d in {d0, d0+1}, d0 = (r0&7)>>1 ----
  const int kc = r0 >> 5;
  const int quad = (r0 >> 3) & 3;
  const int d0 = (r0 & 7) >> 1;
#pragma unroll
  for (int i = 0; i < 2; ++i) {
    int q = i * 256 + t;        // 0..511 = nt*32 + n16*2 + dd
    int nt = q >> 5;            // 0..15
    int n16 = (q >> 1) & 15;
    int dd = q & 1;
    int n = nt * 16 + n16;
    int lane = quad * 16 + n16;
    unsigned word = rn_pair16(S[2 * dd][n], S[2 * dd + 1][n]);
    pk[(m + 1) * 32768 + kc * 4096 + nt * 256 + lane * 4 + (d0 + dd)] = word;
  }
}

// ---------------- Phase 2: slab-pipelined fused kernel ----------------
// MFMA phase: acc[mt] over 8 kc (unroll 2 to cap live zf), weights from wreg,
// z fragments from plane S.
#define MFMA_PHASE(ACC, S)                                                     \
  {                                                                            \
    const unsigned short* pl = zpl + (S) * 16384;                              \
    _Pragma("unroll") for (int mt = 0; mt < 4; ++mt)                           \
        ACC[mt] = (f32x4){0.f, 0.f, 0.f, 0.f};                                 \
    _Pragma("unroll 2") for (int kc = 0; kc < 8; ++kc) {                       \
      short8 zf[4];                                                            \
      _Pragma("unroll") for (int mt = 0; mt < 4; ++mt)                         \
          zf[mt] = *(const short8*)&pl[rd_base[mt] + ((rd_pm[mt] ^ (kc * 4)) * 8)]; \
      _Pragma("unroll") for (int mt = 0; mt < 4; ++mt)                         \
          ACC[mt] = __builtin_amdgcn_mfma_f32_16x16x32_f16(wreg[kc], zf[mt],   \
                                                           ACC[mt], 0, 0, 0); \
    }                                                                          \
  }

// Epilogue: consume ACC (output of a layer for slab S), apply bias/tanh, pack to plane S.
#define EPI_PHASE(ACC, S, BN, BI, DOTANH)                                      \
  {                                                                            \
    unsigned short* pl = zpl + (S) * 16384;                                    \
    float4 bn4 = make_float4(0.f, 0.f, 0.f, 0.f);                              \
    float4 bi4 = make_float4(0.f, 0.f, 0.f, 0.f);                              \
    if (DOTANH) bn4 = *(const float4*)((BN) + colb);                           \
    if ((BI) != nullptr) bi4 = *(const float4*)((BI) + colb);                  \
    _Pragma("unroll") for (int mt = 0; mt < 4; ++mt) {                         \
      float v0 = ACC[mt][0] + bi4.x;                                           \
      float v1 = ACC[mt][1] + bi4.y;                                           \
      float v2 = ACC[mt][2] + bi4.z;                                           \
      float v3 = ACC[mt][3] + bi4.w;                                           \
      if (DOTANH) {                                                            \
        v0 = v0 + tanh_fast(v0) + bn4.x;                                       \
        v1 = v1 + tanh_fast(v1) + bn4.y;                                       \
        v2 = v2 + tanh_fast(v2) + bn4.z;                                       \
        v3 = v3 + tanh_fast(v3) + bn4.w;                                       \
      }                                                                        \
      uint2 zp;                                                                \
      zp.x = rtz_pair16(v0, v1);                                               \
      zp.y = rtz_pair16(v2, v3);                                               \
      *(uint2*)&pl[wr_off[mt]] = zp;                                           \
    }                                                                          \
  }

__global__ __launch_bounds__(1024, 4) void fused2_k(
    const float* __restrict__ x, const unsigned* __restrict__ pk,
    const float* __restrict__ b_in,
    const float* __restrict__ b1, const float* __restrict__ b2,
    const float* __restrict__ b3, const float* __restrict__ b4,
    const float* __restrict__ b_out, float* __restrict__ out) {
  __shared__ unsigned short zpl[4 * 64 * 256];  // 4 z-planes, 128 KB
  const int t = threadIdx.x;
  const int ln = t & 63;
  const int wv = t >> 6;        // wave 0..15, owns cols [wv*16, wv*16+16)
  const int quad = ln >> 4;
  const int n16 = ln & 15;
  const int grow0 = blockIdx.x * 256;

  // ---- stage x as fp16 planes ----
#pragma unroll
  for (int i = 0; i < 16; ++i) {
    int e = i * 4096 + t * 4;
    int r = e >> 8, c = e & 255;
    float4 v = *(const float4*)(x + (grow0 + r) * 256 + c);
    int g = r >> 6, rl = r & 63;
    int idx = g * 16384 + rl * 256 + (((c >> 3) ^ (rl & 31)) * 8) + (c & 7);
    uint2 zp;
    zp.x = rtz_pair16(v.x, v.y);
    zp.y = rtz_pair16(v.z, v.w);
    *(uint2*)&zpl[idx] = zp;
  }

  // ---- per-lane constant offsets (16-bit element units) ----
  const int colb = wv * 16 + quad * 4;
  int rd_base[4], rd_pm[4], wr_off[4];
#pragma unroll
  for (int mt = 0; mt < 4; ++mt) {
    int mm = mt * 16 + n16;
    rd_base[mt] = mm * 256;
    rd_pm[mt] = quad ^ (mm & 31);
    wr_off[mt] = mm * 256 + (((colb >> 3) ^ (mm & 31)) * 8) + (colb & 7);
  }

  __syncthreads();

  f32x4 acc[4];  // single accumulator set: EPI reads it, next MFMA rewrites it

  for (int layer = 0; layer < 5; ++layer) {
    // weights for this layer: one 16-col slice per wave, held in 32 VGPRs,
    // reused across all 4 slabs. Loads issue here; latency hides under the
    // start-of-layer epilogue below.
    const unsigned* pkl = pk + layer * 32768 + wv * 256 + ln * 4;
    short8 wreg[8];
#pragma unroll
    for (int kc = 0; kc < 8; ++kc) wreg[kc] = *(const short8*)(pkl + kc * 4096);

    // phase A: finish (layer-1, slab 3) while MFMAing (layer, slab 0)
    if (layer > 0) {
      const float* bnp = (layer == 1) ? b1 : (layer == 2) ? b2 : (layer == 3) ? b3 : b4;
      const float* bip = (layer == 1) ? b_in : nullptr;
      EPI_PHASE(acc, 3, bnp, bip, true);  // prev layer 0..3 always has tanh
    }
    MFMA_PHASE(acc, 0);
    __syncthreads();

    const float* bn = (layer == 0) ? b1 : (layer == 1) ? b2 : (layer == 2) ? b3 : b4;
    const float* bi0 = (layer == 0) ? b_in : nullptr;
    const bool dt = (layer < 4);

    // phase B
    EPI_PHASE(acc, 0, bn, bi0, dt);
    MFMA_PHASE(acc, 1);
    __syncthreads();
    // phase C
    EPI_PHASE(acc, 1, bn, bi0, dt);
    MFMA_PHASE(acc, 2);
    __syncthreads();
    // phase D
    EPI_PHASE(acc, 2, bn, bi0, dt);
    MFMA_PHASE(acc, 3);
    __syncthreads();
  }
  // drain: final z for slab 3 (layer 4, no tanh)
  EPI_PHASE(acc, 3, (const float*)nullptr, (const float*)nullptr, false);
  __syncthreads();

  // ---- logits: wave group g = wv>>2 handles slab g, k-slice kw = wv&3 ----
  {
    const int g = wv >> 2;
    const int kw = wv & 3;
    f32x4 lacc[4];
#pragma unroll
    for (int mt = 0; mt < 4; ++mt) lacc[mt] = (f32x4){0.f, 0.f, 0.f, 0.f};
    const unsigned* pw = pk + 5 * 32768 + ln * 4;
    const unsigned short* pl = zpl + g * 16384;
#pragma unroll
    for (int kk = 0; kk < 2; ++kk) {
      int kc = kw * 2 + kk;
      short8 wh = *(const short8*)(pw + kc * 256);
#pragma unroll
      for (int mt = 0; mt < 4; ++mt) {
        short8 zf = *(const short8*)&pl[rd_base[mt] + ((rd_pm[mt] ^ (kc * 4)) * 8)];
        lacc[mt] = __builtin_amdgcn_mfma_f32_16x16x32_f16(wh, zf, lacc[mt], 0, 0, 0);
      }
    }
    __syncthreads();  // all z reads done before pbuf overwrites planes
    float* pbuf = (float*)zpl;  // [slab][kw][64 rows][16 cols] = 64 KB
#pragma unroll
    for (int mt = 0; mt < 4; ++mt) {
      int addr = g * 4096 + kw * 1024 + (mt * 16 + n16) * 16 + quad * 4;
      *(f32x4*)&pbuf[addr] = lacc[mt];
    }
    __syncthreads();
    if (t < 256) {
      int g2 = t >> 6;
      int rl = t & 63;
      float lg[10];
      float mx = -1e30f;
#pragma unroll
      for (int j = 0; j < 10; ++j) {
        float s = b_out[j];
#pragma unroll
        for (int k2 = 0; k2 < 4; ++k2) s += pbuf[g2 * 4096 + k2 * 1024 + rl * 16 + j];
        lg[j] = s;
        mx = fmaxf(mx, s);
      }
      float sum = 0.f;
#pragma unroll
      for (int j = 0; j < 10; ++j) {
        lg[j] = __expf(lg[j] - mx);
        sum += lg[j];
      }
      float inv = 1.0f / sum;
      float* op = out + (grow0 + t) * 10;
#pragma unroll
      for (int j = 0; j < 10; ++j) op[j] = lg[j] * inv;
    }
  }
}

extern "C" void kernel_launch(void* const* d_in, const int* in_sizes, int n_in,
                              void* d_out, int out_size, void* d_ws, size_t ws_size,
                              hipStream_t stream) {
  const float* x     = (const float*)d_in[0];
  const float* w_in  = (const float*)d_in[1];
  const float* b_in  = (const float*)d_in[2];
  const float* w_out = (const float*)d_in[3];
  const float* b_out = (const float*)d_in[4];
  const float* w1 = (const float*)d_in[5];
  const float* b1 = (const float*)d_in[6];
  const float* w2 = (const float*)d_in[7];
  const float* b2 = (const float*)d_in[8];
  const float* w3 = (const float*)d_in[9];
  const float* b3 = (const float*)d_in[10];
  const float* w4 = (const float*)d_in[11];
  const float* b4 = (const float*)d_in[12];
  float* out = (float*)d_out;

  unsigned* pk = (unsigned*)d_ws;  // 165888 dwords

  ns_poly_k<<<384, 256, 0, stream>>>(w1, w2, w3, w4, w_in, w_out, pk);
  fused2_k<<<256, 1024, 0, stream>>>(x, pk, b_in, b1, b2, b3, b4, b_out, out);
}

// Round 3
// 223.662 us; speedup vs baseline: 11.3039x; 11.3039x over previous
//
#include <hip/hip_runtime.h>
#include <hip/hip_fp16.h>
#include <math.h>

// B=65536 rows, DIM=256, OUT=10.
// z = x@w_in + b_in; 4x { z = (z + tanh(z) + b_i) @ inv(W_i) }; out = softmax(z@w_out + b_out).
// Newton on a linear system converges in one step => z = c @ W^{-1}.
// Round 17: slab-pipelined persistent fused kernel, register-budget FIXED.
//   256 blocks x 1024 threads (16 waves, 1 block/CU), 256 rows/block = 4 slabs x 64.
//   Wave w owns cols [w*16, w*16+16): per-layer weight slice = 32 VGPRs, loaded ONCE
//   per layer per block and reused for 4 slabs.
//   R15/R16 post-mortem: VGPR_Count=64 both rounds -> compiler's occupancy heuristic
//   targeted 8 waves/EU (ignoring the 128KB-LDS 1-block/CU limit) and spilled.
//   R16 additionally hit rule #20: `unroll 2` made wreg[kc] runtime-indexed -> scratch
//   (MfmaUtil 0.7%, VALU 600us of scratch traffic).
//   Fixes: (1) amdgpu_waves_per_eu(4,4) clamps occupancy -> full 128-VGPR budget;
//   (2) manually unrolled MFMA steps with LITERAL kc (wreg stays in registers),
//   sched_barrier(0) between kc-pairs caps live zf at ~32 VGPRs.
//   z planes: 4 x 64x256 fp16, XOR swizzle idx16(r,k) = r*256 + ((k>>3)^(r&31))*8 + (k&7).

typedef __attribute__((ext_vector_type(8))) short short8;
typedef __attribute__((ext_vector_type(4))) float f32x4;

// ---- helpers ----
__device__ __forceinline__ float tanh_fast(float x) {
#if __has_builtin(__builtin_amdgcn_exp2f)
  float e = __builtin_amdgcn_exp2f(x * 2.8853900817779268f);
#else
  float e = __expf(2.0f * x);
#endif
  return 1.0f - 2.0f * __builtin_amdgcn_rcpf(e + 1.0f);
}
// RNE pair pack (cold path: weights)
__device__ __forceinline__ unsigned rn_pair16(float v0, float v1) {
  __half2 h = __floats2half2_rn(v0, v1);
  return *reinterpret_cast<unsigned*>(&h);
}
// RTZ pair pack, single v_cvt_pkrtz (hot path: z)
__device__ __forceinline__ unsigned rtz_pair16(float v0, float v1) {
#if __has_builtin(__builtin_amdgcn_cvt_pkrtz)
  typedef __fp16 h2v __attribute__((ext_vector_type(2)));
  h2v h = __builtin_amdgcn_cvt_pkrtz(v0, v1);
  return *reinterpret_cast<unsigned*>(&h);
#else
  return rn_pair16(v0, v1);
#endif
}

// ---------------- Phase 1: one kernel, 384 blocks (unchanged) ----------------
// Blocks 0..255: matrix m = bid>>6, 4-row slab r0 = (bid&63)*4:
//   P = 6I -15W +20W^2 -15W^3 +6W^4 -W^5 via 4 Horner steps (mult by original W);
//   pack fp16-RNE into pk layer m+1.
// Blocks 256..383: pack w_in + w_out (at 5*32768, cols>=10 zero).
// pk layout (dwords): layer*32768 + kc*4096 + cg*256 + lane*4 + d;
// word d of lane(quad,n16) = M[kb][n] lo16 | M[kb+1][n] hi16, kb=kc*32+quad*8+2d, n=cg*16+n16.
__global__ __launch_bounds__(256) void ns_poly_k(
    const float* __restrict__ w1, const float* __restrict__ w2,
    const float* __restrict__ w3, const float* __restrict__ w4,
    const float* __restrict__ w_in, const float* __restrict__ w_out,
    unsigned* __restrict__ pk) {
  const int bid = blockIdx.x;
  const int t = threadIdx.x;
  if (bid >= 256) {
    int idx = (bid - 256) * 256 + t;  // 0..32767
    {
      int kc = idx >> 12;
      int nt = (idx >> 8) & 15;
      int lane = (idx >> 2) & 63;
      int d = idx & 3;
      int n = nt * 16 + (lane & 15);
      int kb = kc * 32 + (lane >> 4) * 8 + d * 2;
      pk[idx] = rn_pair16(w_in[kb * 256 + n], w_in[(kb + 1) * 256 + n]);
    }
    int idx2 = idx + 32768;
    if (idx2 < 34816) {
      int r2 = idx2 - 32768;  // 0..2047
      int kc = r2 >> 8;
      int lane = (r2 >> 2) & 63;
      int d = r2 & 3;
      int n = lane & 15;
      int kb = kc * 32 + (lane >> 4) * 8 + d * 2;
      float v0 = (n < 10) ? w_out[kb * 10 + n] : 0.0f;
      float v1 = (n < 10) ? w_out[(kb + 1) * 10 + n] : 0.0f;
      pk[5 * 32768 + r2] = rn_pair16(v0, v1);
    }
    return;
  }
  const int m = bid >> 6;           // matrix 0..3
  const int r0 = (bid & 63) * 4;    // slab start row (4 rows)
  const float* __restrict__ W = (m == 0) ? w1 : (m == 1) ? w2 : (m == 2) ? w3 : w4;
  __shared__ float S[4][256];

  // init: P = 6I - W (slab rows r0..r0+3)
#pragma unroll
  for (int i = 0; i < 4; ++i) {
    int e = i * 256 + t;
    int r = e >> 8, c = e & 255;
    S[r][c] = (((r0 + r) == c) ? 6.0f : 0.0f) - W[(r0 + r) * 256 + c];
  }
  __syncthreads();

  const float coef[4] = {-15.0f, 20.0f, -15.0f, 6.0f};
#pragma unroll
  for (int step = 0; step < 4; ++step) {
    float acc[4];
#pragma unroll
    for (int r = 0; r < 4; ++r) acc[r] = 0.0f;
    for (int k = 0; k < 256; k += 4) {
      float4 sv[4];
#pragma unroll
      for (int r = 0; r < 4; ++r) sv[r] = *(const float4*)&S[r][k];
      float wv0 = W[(k + 0) * 256 + t];
      float wv1 = W[(k + 1) * 256 + t];
      float wv2 = W[(k + 2) * 256 + t];
      float wv3 = W[(k + 3) * 256 + t];
#pragma unroll
      for (int r = 0; r < 4; ++r) {
        acc[r] = fmaf(sv[r].x, wv0, acc[r]);
        acc[r] = fmaf(sv[r].y, wv1, acc[r]);
        acc[r] = fmaf(sv[r].z, wv2, acc[r]);
        acc[r] = fmaf(sv[r].w, wv3, acc[r]);
      }
    }
    __syncthreads();
    float cdiag = coef[step];
#pragma unroll
    for (int r = 0; r < 4; ++r)
      S[r][t] = acc[r] + (((r0 + r) == t) ? cdiag : 0.0f);
    __syncthreads();
  }

  // ---- pack slab: kc = r0>>5, quad = (r0>>3)&3, d in {d0, d0+1}, d0 = (r0&7)>>1 ----
  const int kc = r0 >> 5;
  const int quad = (r0 >> 3) & 3;
  const int d0 = (r0 & 7) >> 1;
#pragma unroll
  for (int i = 0; i < 2; ++i) {
    int q = i * 256 + t;        // 0..511 = nt*32 + n16*2 + dd
    int nt = q >> 5;            // 0..15
    int n16 = (q >> 1) & 15;
    int dd = q & 1;
    int n = nt * 16 + n16;
    int lane = quad * 16 + n16;
    unsigned word = rn_pair16(S[2 * dd][n], S[2 * dd + 1][n]);
    pk[(m + 1) * 32768 + kc * 4096 + nt * 256 + lane * 4 + (d0 + dd)] = word;
  }
}

// ---------------- Phase 2: slab-pipelined fused kernel ----------------
// One kc step, KC is a LITERAL (wreg/acc indices compile-time -> registers).
#define MFMA_STEP(ACC, PL, KC)                                                     \
  {                                                                                \
    short8 zf0 = *(const short8*)&PL[rd_base[0] + ((rd_pm[0] ^ ((KC) * 4)) * 8)];  \
    short8 zf1 = *(const short8*)&PL[rd_base[1] + ((rd_pm[1] ^ ((KC) * 4)) * 8)];  \
    short8 zf2 = *(const short8*)&PL[rd_base[2] + ((rd_pm[2] ^ ((KC) * 4)) * 8)];  \
    short8 zf3 = *(const short8*)&PL[rd_base[3] + ((rd_pm[3] ^ ((KC) * 4)) * 8)];  \
    ACC[0] = __builtin_amdgcn_mfma_f32_16x16x32_f16(wreg[KC], zf0, ACC[0], 0, 0, 0); \
    ACC[1] = __builtin_amdgcn_mfma_f32_16x16x32_f16(wreg[KC], zf1, ACC[1], 0, 0, 0); \
    ACC[2] = __builtin_amdgcn_mfma_f32_16x16x32_f16(wreg[KC], zf2, ACC[2], 0, 0, 0); \
    ACC[3] = __builtin_amdgcn_mfma_f32_16x16x32_f16(wreg[KC], zf3, ACC[3], 0, 0, 0); \
  }

// MFMA phase over 8 kc; sched_barrier(0) between pairs caps live zf at ~32 VGPRs
// (prevents the R15 hoist-all-32-ds_reads pressure spike).
#define MFMA_PHASE(ACC, S)                                                     \
  {                                                                            \
    const unsigned short* pl = zpl + (S) * 16384;                              \
    ACC[0] = (f32x4){0.f, 0.f, 0.f, 0.f};                                      \
    ACC[1] = (f32x4){0.f, 0.f, 0.f, 0.f};                                      \
    ACC[2] = (f32x4){0.f, 0.f, 0.f, 0.f};                                      \
    ACC[3] = (f32x4){0.f, 0.f, 0.f, 0.f};                                      \
    MFMA_STEP(ACC, pl, 0);                                                     \
    MFMA_STEP(ACC, pl, 1);                                                     \
    __builtin_amdgcn_sched_barrier(0);                                         \
    MFMA_STEP(ACC, pl, 2);                                                     \
    MFMA_STEP(ACC, pl, 3);                                                     \
    __builtin_amdgcn_sched_barrier(0);                                         \
    MFMA_STEP(ACC, pl, 4);                                                     \
    MFMA_STEP(ACC, pl, 5);                                                     \
    __builtin_amdgcn_sched_barrier(0);                                         \
    MFMA_STEP(ACC, pl, 6);                                                     \
    MFMA_STEP(ACC, pl, 7);                                                     \
  }

// Epilogue: consume ACC (output of a layer for slab S), apply bias/tanh, pack to plane S.
#define EPI_PHASE(ACC, S, BN, BI, DOTANH)                                      \
  {                                                                            \
    unsigned short* pl = zpl + (S) * 16384;                                    \
    float4 bn4 = make_float4(0.f, 0.f, 0.f, 0.f);                              \
    float4 bi4 = make_float4(0.f, 0.f, 0.f, 0.f);                              \
    if (DOTANH) bn4 = *(const float4*)((BN) + colb);                           \
    if ((BI) != nullptr) bi4 = *(const float4*)((BI) + colb);                  \
    _Pragma("unroll") for (int mt = 0; mt < 4; ++mt) {                         \
      float v0 = ACC[mt][0] + bi4.x;                                           \
      float v1 = ACC[mt][1] + bi4.y;                                           \
      float v2 = ACC[mt][2] + bi4.z;                                           \
      float v3 = ACC[mt][3] + bi4.w;                                           \
      if (DOTANH) {                                                            \
        v0 = v0 + tanh_fast(v0) + bn4.x;                                       \
        v1 = v1 + tanh_fast(v1) + bn4.y;                                       \
        v2 = v2 + tanh_fast(v2) + bn4.z;                                       \
        v3 = v3 + tanh_fast(v3) + bn4.w;                                       \
      }                                                                        \
      uint2 zp;                                                                \
      zp.x = rtz_pair16(v0, v1);                                               \
      zp.y = rtz_pair16(v2, v3);                                               \
      *(uint2*)&pl[wr_off[mt]] = zp;                                           \
    }                                                                          \
  }

__global__ __launch_bounds__(1024)
__attribute__((amdgpu_waves_per_eu(4, 4)))  // LDS caps us at 1 blk/CU anyway; give allocator 128 VGPRs
void fused2_k(
    const float* __restrict__ x, const unsigned* __restrict__ pk,
    const float* __restrict__ b_in,
    const float* __restrict__ b1, const float* __restrict__ b2,
    const float* __restrict__ b3, const float* __restrict__ b4,
    const float* __restrict__ b_out, float* __restrict__ out) {
  __shared__ unsigned short zpl[4 * 64 * 256];  // 4 z-planes, 128 KB
  const int t = threadIdx.x;
  const int ln = t & 63;
  const int wv = t >> 6;        // wave 0..15, owns cols [wv*16, wv*16+16)
  const int quad = ln >> 4;
  const int n16 = ln & 15;
  const int grow0 = blockIdx.x * 256;

  // ---- stage x as fp16 planes ----
#pragma unroll
  for (int i = 0; i < 16; ++i) {
    int e = i * 4096 + t * 4;
    int r = e >> 8, c = e & 255;
    float4 v = *(const float4*)(x + (grow0 + r) * 256 + c);
    int g = r >> 6, rl = r & 63;
    int idx = g * 16384 + rl * 256 + (((c >> 3) ^ (rl & 31)) * 8) + (c & 7);
    uint2 zp;
    zp.x = rtz_pair16(v.x, v.y);
    zp.y = rtz_pair16(v.z, v.w);
    *(uint2*)&zpl[idx] = zp;
  }

  // ---- per-lane constant offsets (16-bit element units) ----
  const int colb = wv * 16 + quad * 4;
  int rd_base[4], rd_pm[4], wr_off[4];
#pragma unroll
  for (int mt = 0; mt < 4; ++mt) {
    int mm = mt * 16 + n16;
    rd_base[mt] = mm * 256;
    rd_pm[mt] = quad ^ (mm & 31);
    wr_off[mt] = mm * 256 + (((colb >> 3) ^ (mm & 31)) * 8) + (colb & 7);
  }

  __syncthreads();

  f32x4 acc[4];  // single accumulator set: EPI reads it, next MFMA rewrites it

  for (int layer = 0; layer < 5; ++layer) {
    // weights for this layer: one 16-col slice per wave, held in 32 VGPRs,
    // reused across all 4 slabs. Loads issue here; latency hides under the
    // start-of-layer epilogue below.
    const unsigned* pkl = pk + layer * 32768 + wv * 256 + ln * 4;
    short8 wreg[8];
#pragma unroll
    for (int kc = 0; kc < 8; ++kc) wreg[kc] = *(const short8*)(pkl + kc * 4096);

    // phase A: finish (layer-1, slab 3) while MFMAing (layer, slab 0)
    if (layer > 0) {
      const float* bnp = (layer == 1) ? b1 : (layer == 2) ? b2 : (layer == 3) ? b3 : b4;
      const float* bip = (layer == 1) ? b_in : nullptr;
      EPI_PHASE(acc, 3, bnp, bip, true);  // prev layer 0..3 always has tanh
    }
    MFMA_PHASE(acc, 0);
    __syncthreads();

    const float* bn = (layer == 0) ? b1 : (layer == 1) ? b2 : (layer == 2) ? b3 : b4;
    const float* bi0 = (layer == 0) ? b_in : nullptr;
    const bool dt = (layer < 4);

    // phase B
    EPI_PHASE(acc, 0, bn, bi0, dt);
    MFMA_PHASE(acc, 1);
    __syncthreads();
    // phase C
    EPI_PHASE(acc, 1, bn, bi0, dt);
    MFMA_PHASE(acc, 2);
    __syncthreads();
    // phase D
    EPI_PHASE(acc, 2, bn, bi0, dt);
    MFMA_PHASE(acc, 3);
    __syncthreads();
  }
  // drain: final z for slab 3 (layer 4, no tanh)
  EPI_PHASE(acc, 3, (const float*)nullptr, (const float*)nullptr, false);
  __syncthreads();

  // ---- logits: wave group g = wv>>2 handles slab g, k-slice kw = wv&3 ----
  {
    const int g = wv >> 2;
    const int kw = wv & 3;
    f32x4 lacc[4];
#pragma unroll
    for (int mt = 0; mt < 4; ++mt) lacc[mt] = (f32x4){0.f, 0.f, 0.f, 0.f};
    const unsigned* pw = pk + 5 * 32768 + ln * 4;
    const unsigned short* pl = zpl + g * 16384;
#pragma unroll
    for (int kk = 0; kk < 2; ++kk) {
      int kc = kw * 2 + kk;
      short8 wh = *(const short8*)(pw + kc * 256);
#pragma unroll
      for (int mt = 0; mt < 4; ++mt) {
        short8 zf = *(const short8*)&pl[rd_base[mt] + ((rd_pm[mt] ^ (kc * 4)) * 8)];
        lacc[mt] = __builtin_amdgcn_mfma_f32_16x16x32_f16(wh, zf, lacc[mt], 0, 0, 0);
      }
    }
    __syncthreads();  // all z reads done before pbuf overwrites planes
    float* pbuf = (float*)zpl;  // [slab][kw][64 rows][16 cols] = 64 KB
#pragma unroll
    for (int mt = 0; mt < 4; ++mt) {
      int addr = g * 4096 + kw * 1024 + (mt * 16 + n16) * 16 + quad * 4;
      *(f32x4*)&pbuf[addr] = lacc[mt];
    }
    __syncthreads();
    if (t < 256) {
      int g2 = t >> 6;
      int rl = t & 63;
      float lg[10];
      float mx = -1e30f;
#pragma unroll
      for (int j = 0; j < 10; ++j) {
        float s = b_out[j];
#pragma unroll
        for (int k2 = 0; k2 < 4; ++k2) s += pbuf[g2 * 4096 + k2 * 1024 + rl * 16 + j];
        lg[j] = s;
        mx = fmaxf(mx, s);
      }
      float sum = 0.f;
#pragma unroll
      for (int j = 0; j < 10; ++j) {
        lg[j] = __expf(lg[j] - mx);
        sum += lg[j];
      }
      float inv = 1.0f / sum;
      float* op = out + (grow0 + t) * 10;
#pragma unroll
      for (int j = 0; j < 10; ++j) op[j] = lg[j] * inv;
    }
  }
}

extern "C" void kernel_launch(void* const* d_in, const int* in_sizes, int n_in,
                              void* d_out, int out_size, void* d_ws, size_t ws_size,
                              hipStream_t stream) {
  const float* x     = (const float*)d_in[0];
  const float* w_in  = (const float*)d_in[1];
  const float* b_in  = (const float*)d_in[2];
  const float* w_out = (const float*)d_in[3];
  const float* b_out = (const float*)d_in[4];
  const float* w1 = (const float*)d_in[5];
  const float* b1 = (const float*)d_in[6];
  const float* w2 = (const float*)d_in[7];
  const float* b2 = (const float*)d_in[8];
  const float* w3 = (const float*)d_in[9];
  const float* b3 = (const float*)d_in[10];
  const float* w4 = (const float*)d_in[11];
  const float* b4 = (const float*)d_in[12];
  float* out = (float*)d_out;

  unsigned* pk = (unsigned*)d_ws;  // 165888 dwords

  ns_poly_k<<<384, 256, 0, stream>>>(w1, w2, w3, w4, w_in, w_out, pk);
  fused2_k<<<256, 1024, 0, stream>>>(x, pk, b_in, b1, b2, b3, b4, b_out, out);
}

// Round 4
// 205.603 us; speedup vs baseline: 12.2968x; 1.0878x over previous
//
#include <hip/hip_runtime.h>
#include <hip/hip_fp16.h>
#include <math.h>

// B=65536 rows, DIM=256, OUT=10.
// z = x@w_in + b_in; 4x { z = (z + tanh(z) + b_i) @ inv(W_i) }; out = softmax(z@w_out + b_out).
// Newton on a linear system converges in one step => z = c @ W^{-1}.
// Round 18: fused3_k — 256-VGPR budget, register-resident weights, two-tile skew.
//   R15-R17 post-mortem: rocprof VGPR_Count=64 is ARCH-only; acc lives in AGPRs (64)
//   -> round-10 was at exactly 128/128 unified (4 waves/EU cap). All >64-arch designs
//   spilled. Round-10's real stall: wh[nt] streamed from L2 inside the kc loop
//   (~200cyc latency per step, 4 waves/SIMD -> MfmaUtil 24%).
//   fused3_k: 512 blocks x 256 thr (4 waves), amdgpu_waves_per_eu(2,2) -> 256-reg cap.
//   wreg[4][8] (128 VGPRs) = this wave's full 64-col weight slice, loaded ONCE per
//   layer from L2, amortized over TWO 64-row tiles (2 z-planes, 64 KB LDS, 2 blk/CU).
//   Next layer's wreg loads issue before E1 -> L2 latency hides under tanh epilogue.
//   Schedule per layer: M0 |bar| E0,M1 |bar| E1 -> 2 barriers per 128 rows (half of
//   round-10) and every inter-barrier region has EPI||MFMA overlap.
//   kc fully unrolled (literal wreg idx, rule #20) + sched_barrier(0) per step.
//   z planes: 64x256 fp16, XOR swizzle idx16(r,k) = r*256 + ((k>>3)^(r&31))*8 + (k&7).

typedef __attribute__((ext_vector_type(8))) short short8;
typedef __attribute__((ext_vector_type(4))) float f32x4;

// ---- helpers ----
__device__ __forceinline__ float tanh_fast(float x) {
#if __has_builtin(__builtin_amdgcn_exp2f)
  float e = __builtin_amdgcn_exp2f(x * 2.8853900817779268f);
#else
  float e = __expf(2.0f * x);
#endif
  return 1.0f - 2.0f * __builtin_amdgcn_rcpf(e + 1.0f);
}
// RNE pair pack (cold path: weights)
__device__ __forceinline__ unsigned rn_pair16(float v0, float v1) {
  __half2 h = __floats2half2_rn(v0, v1);
  return *reinterpret_cast<unsigned*>(&h);
}
// RTZ pair pack, single v_cvt_pkrtz (hot path: z)
__device__ __forceinline__ unsigned rtz_pair16(float v0, float v1) {
#if __has_builtin(__builtin_amdgcn_cvt_pkrtz)
  typedef __fp16 h2v __attribute__((ext_vector_type(2)));
  h2v h = __builtin_amdgcn_cvt_pkrtz(v0, v1);
  return *reinterpret_cast<unsigned*>(&h);
#else
  return rn_pair16(v0, v1);
#endif
}

// ---------------- Phase 1: one kernel, 384 blocks (unchanged, proven) ----------------
// Blocks 0..255: matrix m = bid>>6, 4-row slab r0 = (bid&63)*4:
//   P = 6I -15W +20W^2 -15W^3 +6W^4 -W^5 via 4 Horner steps (mult by original W);
//   pack fp16-RNE into pk layer m+1.
// Blocks 256..383: pack w_in + w_out (at 5*32768, cols>=10 zero).
// pk layout (dwords): layer*32768 + kc*4096 + cg*256 + lane*4 + d;
// word d of lane(quad,n16) = M[kb][n] lo16 | M[kb+1][n] hi16, kb=kc*32+quad*8+2d, n=cg*16+n16.
__global__ __launch_bounds__(256) void ns_poly_k(
    const float* __restrict__ w1, const float* __restrict__ w2,
    const float* __restrict__ w3, const float* __restrict__ w4,
    const float* __restrict__ w_in, const float* __restrict__ w_out,
    unsigned* __restrict__ pk) {
  const int bid = blockIdx.x;
  const int t = threadIdx.x;
  if (bid >= 256) {
    int idx = (bid - 256) * 256 + t;  // 0..32767
    {
      int kc = idx >> 12;
      int nt = (idx >> 8) & 15;
      int lane = (idx >> 2) & 63;
      int d = idx & 3;
      int n = nt * 16 + (lane & 15);
      int kb = kc * 32 + (lane >> 4) * 8 + d * 2;
      pk[idx] = rn_pair16(w_in[kb * 256 + n], w_in[(kb + 1) * 256 + n]);
    }
    int idx2 = idx + 32768;
    if (idx2 < 34816) {
      int r2 = idx2 - 32768;  // 0..2047
      int kc = r2 >> 8;
      int lane = (r2 >> 2) & 63;
      int d = r2 & 3;
      int n = lane & 15;
      int kb = kc * 32 + (lane >> 4) * 8 + d * 2;
      float v0 = (n < 10) ? w_out[kb * 10 + n] : 0.0f;
      float v1 = (n < 10) ? w_out[(kb + 1) * 10 + n] : 0.0f;
      pk[5 * 32768 + r2] = rn_pair16(v0, v1);
    }
    return;
  }
  const int m = bid >> 6;           // matrix 0..3
  const int r0 = (bid & 63) * 4;    // slab start row (4 rows)
  const float* __restrict__ W = (m == 0) ? w1 : (m == 1) ? w2 : (m == 2) ? w3 : w4;
  __shared__ float S[4][256];

  // init: P = 6I - W (slab rows r0..r0+3)
#pragma unroll
  for (int i = 0; i < 4; ++i) {
    int e = i * 256 + t;
    int r = e >> 8, c = e & 255;
    S[r][c] = (((r0 + r) == c) ? 6.0f : 0.0f) - W[(r0 + r) * 256 + c];
  }
  __syncthreads();

  const float coef[4] = {-15.0f, 20.0f, -15.0f, 6.0f};
#pragma unroll
  for (int step = 0; step < 4; ++step) {
    float acc[4];
#pragma unroll
    for (int r = 0; r < 4; ++r) acc[r] = 0.0f;
    for (int k = 0; k < 256; k += 4) {
      float4 sv[4];
#pragma unroll
      for (int r = 0; r < 4; ++r) sv[r] = *(const float4*)&S[r][k];
      float wv0 = W[(k + 0) * 256 + t];
      float wv1 = W[(k + 1) * 256 + t];
      float wv2 = W[(k + 2) * 256 + t];
      float wv3 = W[(k + 3) * 256 + t];
#pragma unroll
      for (int r = 0; r < 4; ++r) {
        acc[r] = fmaf(sv[r].x, wv0, acc[r]);
        acc[r] = fmaf(sv[r].y, wv1, acc[r]);
        acc[r] = fmaf(sv[r].z, wv2, acc[r]);
        acc[r] = fmaf(sv[r].w, wv3, acc[r]);
      }
    }
    __syncthreads();
    float cdiag = coef[step];
#pragma unroll
    for (int r = 0; r < 4; ++r)
      S[r][t] = acc[r] + (((r0 + r) == t) ? cdiag : 0.0f);
    __syncthreads();
  }

  // ---- pack slab: kc = r0>>5, quad = (r0>>3)&3, d in {d0, d0+1}, d0 = (r0&7)>>1 ----
  const int kc = r0 >> 5;
  const int quad = (r0 >> 3) & 3;
  const int d0 = (r0 & 7) >> 1;
#pragma unroll
  for (int i = 0; i < 2; ++i) {
    int q = i * 256 + t;        // 0..511 = nt*32 + n16*2 + dd
    int nt = q >> 5;            // 0..15
    int n16 = (q >> 1) & 15;
    int dd = q & 1;
    int n = nt * 16 + n16;
    int lane = quad * 16 + n16;
    unsigned word = rn_pair16(S[2 * dd][n], S[2 * dd + 1][n]);
    pk[(m + 1) * 32768 + kc * 4096 + nt * 256 + lane * 4 + (d0 + dd)] = word;
  }
}

// ---------------- Phase 2: fused3_k ----------------
// MFMA phase over plane PL: 8 kc fully unrolled (literal wreg idx), 4 ds_read_b128 +
// 16 MFMA per step, sched_barrier(0) per step caps zf hoisting (live zf = 16 VGPRs).
#define M_PHASE(PL)                                                            \
  {                                                                            \
    _Pragma("unroll") for (int mt = 0; mt < 4; ++mt)                           \
      _Pragma("unroll") for (int nt = 0; nt < 4; ++nt)                         \
        acc[mt][nt] = (f32x4){0.f, 0.f, 0.f, 0.f};                             \
    _Pragma("unroll") for (int kc = 0; kc < 8; ++kc) {                         \
      short8 zf[4];                                                            \
      _Pragma("unroll") for (int mt = 0; mt < 4; ++mt) {                       \
        int mm = mt * 16 + n16;                                                \
        zf[mt] = *(const short8*)&(PL)[mm * 256 + (((kc * 4 + quad) ^ (mm & 31)) * 8)]; \
      }                                                                        \
      _Pragma("unroll") for (int mt = 0; mt < 4; ++mt)                         \
        _Pragma("unroll") for (int nt = 0; nt < 4; ++nt)                       \
          acc[mt][nt] = __builtin_amdgcn_mfma_f32_16x16x32_f16(                \
              wreg[nt][kc], zf[mt], acc[mt][nt], 0, 0, 0);                     \
      __builtin_amdgcn_sched_barrier(0);                                       \
    }                                                                          \
  }

// Epilogue into plane PL: round-10 geometry (colb per nt), bias/tanh, cvt_pkrtz pack.
#define E_PHASE(PL, BN, BI, DOTANH)                                            \
  {                                                                            \
    _Pragma("unroll") for (int nt = 0; nt < 4; ++nt) {                         \
      int colb = wv * 64 + nt * 16 + quad * 4;                                 \
      float4 bi4 = make_float4(0.f, 0.f, 0.f, 0.f);                            \
      float4 bn4 = make_float4(0.f, 0.f, 0.f, 0.f);                            \
      if ((BI) != nullptr) bi4 = *(const float4*)((BI) + colb);                \
      if (DOTANH) bn4 = *(const float4*)((BN) + colb);                         \
      _Pragma("unroll") for (int mt = 0; mt < 4; ++mt) {                       \
        int row = mt * 16 + n16;                                               \
        float v0 = acc[mt][nt][0] + bi4.x;                                     \
        float v1 = acc[mt][nt][1] + bi4.y;                                     \
        float v2 = acc[mt][nt][2] + bi4.z;                                     \
        float v3 = acc[mt][nt][3] + bi4.w;                                     \
        if (DOTANH) {                                                          \
          v0 = v0 + tanh_fast(v0) + bn4.x;                                     \
          v1 = v1 + tanh_fast(v1) + bn4.y;                                     \
          v2 = v2 + tanh_fast(v2) + bn4.z;                                     \
          v3 = v3 + tanh_fast(v3) + bn4.w;                                     \
        }                                                                      \
        int idx = row * 256 + (((colb >> 3) ^ (row & 31)) * 8) + (colb & 7);   \
        uint2 zp;                                                              \
        zp.x = rtz_pair16(v0, v1);                                             \
        zp.y = rtz_pair16(v2, v3);                                             \
        *(uint2*)&(PL)[idx] = zp;                                              \
      }                                                                        \
    }                                                                          \
  }

// Load this wave's full 64-col weight slice for LAYER into wreg (128 VGPRs).
#define LOAD_WREG(LAYER)                                                       \
  {                                                                            \
    const unsigned* pkl = pk + (LAYER) * 32768 + wv * 1024 + ln * 4;           \
    _Pragma("unroll") for (int nt = 0; nt < 4; ++nt)                           \
      _Pragma("unroll") for (int kc = 0; kc < 8; ++kc)                         \
        wreg[nt][kc] = *(const short8*)(pkl + kc * 4096 + nt * 256);           \
  }

__global__ __launch_bounds__(256)
__attribute__((amdgpu_waves_per_eu(2, 2)))  // 2 waves/EU -> 256-reg unified budget
void fused3_k(
    const float* __restrict__ x, const unsigned* __restrict__ pk,
    const float* __restrict__ b_in,
    const float* __restrict__ b1, const float* __restrict__ b2,
    const float* __restrict__ b3, const float* __restrict__ b4,
    const float* __restrict__ b_out, float* __restrict__ out) {
  __shared__ unsigned short zpl[2 * 64 * 256];  // two z-planes, 64 KB
  const int t = threadIdx.x;
  const int ln = t & 63;
  const int wv = t >> 6;        // wave 0..3, owns cols [wv*64, wv*64+64)
  const int quad = ln >> 4;
  const int n16 = ln & 15;
  const int grow0 = blockIdx.x * 128;  // 128 rows/block (two 64-row tiles)

  short8 wreg[4][8];  // [nt][kc] — this wave's weight slice, 128 VGPRs
  f32x4 acc[4][4];    // [mt][nt] — 64 regs (AGPR side)

  LOAD_WREG(0);  // layer-0 weights in flight during x staging

  // ---- stage x as fp16 into both planes ----
#pragma unroll
  for (int i = 0; i < 32; ++i) {
    int e = i * 1024 + t * 4;
    int r = e >> 8, c = e & 255;     // r 0..127
    float4 v = *(const float4*)(x + (grow0 + r) * 256 + c);
    int u = r >> 6, rl = r & 63;
    int idx = u * 16384 + rl * 256 + (((c >> 3) ^ (rl & 31)) * 8) + (c & 7);
    uint2 zp;
    zp.x = rtz_pair16(v.x, v.y);
    zp.y = rtz_pair16(v.z, v.w);
    *(uint2*)&zpl[idx] = zp;
  }
  __syncthreads();

  unsigned short* pl0 = zpl;
  unsigned short* pl1 = zpl + 16384;
  const float* bnv[4] = {b1, b2, b3, b4};

  for (int layer = 0; layer < 5; ++layer) {
    const float* bn = (layer < 4) ? bnv[layer] : nullptr;
    const float* bi0 = (layer == 0) ? b_in : nullptr;
    const bool dt = (layer < 4);

    M_PHASE(pl0);                       // tile 0 MFMA (wreg + LDS only, no vmcnt)
    __syncthreads();
    E_PHASE(pl0, bn, bi0, dt);          // tile 0 epilogue ...
    M_PHASE(pl1);                       // ... overlapped with tile 1 MFMA
    __syncthreads();
    if (layer < 4) LOAD_WREG(layer + 1);  // wreg dead; L2 latency hides under E1
    E_PHASE(pl1, bn, bi0, dt);          // tile 1 epilogue
  }
  __syncthreads();

  // ---- logits: wave wv reduces k-slice [wv*64, wv*64+64), both tiles ----
  {
    f32x4 lacc[2][4];
#pragma unroll
    for (int u = 0; u < 2; ++u)
#pragma unroll
      for (int mt = 0; mt < 4; ++mt) lacc[u][mt] = (f32x4){0.f, 0.f, 0.f, 0.f};
    const unsigned* pw = pk + 5 * 32768 + ln * 4;
#pragma unroll
    for (int kk = 0; kk < 2; ++kk) {
      int kc = wv * 2 + kk;
      short8 wh = *(const short8*)(pw + kc * 256);
#pragma unroll
      for (int u = 0; u < 2; ++u) {
        const unsigned short* pl = zpl + u * 16384;
#pragma unroll
        for (int mt = 0; mt < 4; ++mt) {
          int mm = mt * 16 + n16;
          short8 zf = *(const short8*)&pl[mm * 256 + (((kc * 4 + quad) ^ (mm & 31)) * 8)];
          lacc[u][mt] = __builtin_amdgcn_mfma_f32_16x16x32_f16(wh, zf, lacc[u][mt], 0, 0, 0);
        }
      }
    }
    __syncthreads();  // all z reads done before pbuf overwrites planes
    // pbuf_u overlays plane u: [wave][64 rows][16 cols] floats = 16 KB per tile
#pragma unroll
    for (int u = 0; u < 2; ++u) {
      float* pbuf = (float*)(zpl + u * 16384);
#pragma unroll
      for (int mt = 0; mt < 4; ++mt) {
        int addr = wv * 1024 + (mt * 16 + n16) * 16 + quad * 4;
        *(f32x4*)&pbuf[addr] = lacc[u][mt];
      }
    }
    __syncthreads();
    if (t < 128) {
      int u = t >> 6;
      int rl = t & 63;
      const float* pbuf = (const float*)(zpl + u * 16384);
      float lg[10];
      float mx = -1e30f;
#pragma unroll
      for (int j = 0; j < 10; ++j) {
        float s = b_out[j];
#pragma unroll
        for (int w2 = 0; w2 < 4; ++w2) s += pbuf[w2 * 1024 + rl * 16 + j];
        lg[j] = s;
        mx = fmaxf(mx, s);
      }
      float sum = 0.f;
#pragma unroll
      for (int j = 0; j < 10; ++j) {
        lg[j] = __expf(lg[j] - mx);
        sum += lg[j];
      }
      float inv = 1.0f / sum;
      float* op = out + (grow0 + t) * 10;
#pragma unroll
      for (int j = 0; j < 10; ++j) op[j] = lg[j] * inv;
    }
  }
}

extern "C" void kernel_launch(void* const* d_in, const int* in_sizes, int n_in,
                              void* d_out, int out_size, void* d_ws, size_t ws_size,
                              hipStream_t stream) {
  const float* x     = (const float*)d_in[0];
  const float* w_in  = (const float*)d_in[1];
  const float* b_in  = (const float*)d_in[2];
  const float* w_out = (const float*)d_in[3];
  const float* b_out = (const float*)d_in[4];
  const float* w1 = (const float*)d_in[5];
  const float* b1 = (const float*)d_in[6];
  const float* w2 = (const float*)d_in[7];
  const float* b2 = (const float*)d_in[8];
  const float* w3 = (const float*)d_in[9];
  const float* b3 = (const float*)d_in[10];
  const float* w4 = (const float*)d_in[11];
  const float* b4 = (const float*)d_in[12];
  float* out = (float*)d_out;

  unsigned* pk = (unsigned*)d_ws;  // 165888 dwords

  ns_poly_k<<<384, 256, 0, stream>>>(w1, w2, w3, w4, w_in, w_out, pk);
  fused3_k<<<512, 256, 0, stream>>>(x, pk, b_in, b1, b2, b3, b4, b_out, out);
}